// Round 4
// baseline (33.387 us; speedup 1.0000x reference)
//
#include <hip/hip_runtime.h>

// PewLSTM HS=1, lane-pair systolic (even lane = layer1 @ t, odd = layer2 @ t-1,
// h handed off via DPP quad_perm). This round:
//  - phase1(chunk c+1) interleaved into phase2(chunk c) per step (SW pipeline)
//  - weights pre-scaled by -log2e (-2log2e for tanh gate): exp2 eats gates raw
//  - fused-denominator c/h updates: 7 trans/step (5 exp2 + 2 rcp) vs 10

constexpr int BB  = 32768;
constexpr int TT  = 168;
constexpr int CHS = 8;            // timesteps per chunk
constexpr int CHV = 10;           // float4 per chunk (8*5/4)
constexpr int NCH = 21;           // chunks

#define LOG2E  1.44269504088896341f
#define NEG2L  (-2.88539008177792681f)
#define ACLAMP 40.0f              // exp2-arg clamp: den <= 2^120, no overflow

__device__ __forceinline__ float lane_swap(float x) {
    // xor-1 swap via DPP quad_perm(1,0,3,2)
    return __int_as_float(
        __builtin_amdgcn_mov_dpp(__float_as_int(x), 0xB1, 0xF, 0xF, true));
}

__global__ __launch_bounds__(64, 1) void pewlstm_kernel(
    const float* __restrict__ in,
    const float* __restrict__ W1ih, const float* __restrict__ W1hh,
    const float* __restrict__ W1wh, const float* __restrict__ b1,
    const float* __restrict__ W2ih, const float* __restrict__ W2hh,
    const float* __restrict__ W2wh, const float* __restrict__ b2,
    const float* __restrict__ fcw, const float* __restrict__ fcb,
    float* __restrict__ out)
{
    const int tid = blockIdx.x * 64 + threadIdx.x;
    const int b   = tid >> 1;
    const int l2  = tid & 1;
    const float l2f = l2 ? 1.0f : 0.0f;

    const float* Wih = l2 ? W2ih : W1ih;
    const float* Whh = l2 ? W2hh : W1hh;
    const float* Wwh = l2 ? W2wh : W1wh;
    const float* Bv  = l2 ? b2   : b1;

    // gate order [i, f, g(tanh), o]; pre-scale so exp2(gate) = e^{-a} / e^{-2a}
    float wih[4], whh[4], bbv[4], wwh[16];
#pragma unroll
    for (int g = 0; g < 4; ++g) {
        const float s = (g == 2) ? NEG2L : -LOG2E;
        wih[g] = Wih[g] * s; whh[g] = Whh[g] * s; bbv[g] = Bv[g] * s;
    }
#pragma unroll
    for (int k = 0; k < 16; ++k) {
        const float s = ((k & 3) == 2) ? NEG2L : -LOG2E;
        wwh[k] = Wwh[k] * s;
    }
    const float fw = fcw[0], fbv = fcb[0];

    const float4* __restrict__ row =
        reinterpret_cast<const float4*>(in + (size_t)b * (TT * 5));
    float4* orow = reinterpret_cast<float4*>(out + (size_t)b * TT);

    float4 pref[CHV];
#pragma unroll
    for (int i = 0; i < CHV; ++i) pref[i] = row[i];   // chunk 0

    float h = 0.f, cc = 0.f, h1x = 0.f;
    float xc0 = 0.f, xc1 = 0.f, xc2 = 0.f, xc3 = 0.f;  // prev chunk's last weather
    float ob[CHS];
    float preA[CHS][4], preB[CHS][4];
    float cur[CHS * 5];

    auto commit = [&]() {
#pragma unroll
        for (int i = 0; i < CHV; ++i) {
            float4 v = pref[i];
            cur[4*i+0] = v.x; cur[4*i+1] = v.y;
            cur[4*i+2] = v.z; cur[4*i+3] = v.w;
        }
    };
    auto issue = [&](int c2) {
        const float4* nr = row + c2 * CHV;
#pragma unroll
        for (int i = 0; i < CHV; ++i) pref[i] = nr[i];
    };

    // phase2(chunk c, pre=pC) interleaved with phase1(chunk in cur -> pN)
    auto run_chunk = [&](float (&pC)[CHS][4], float (&pN)[CHS][4],
                         int c, bool buildNext) {
        const bool is0 = (c == 0);
#pragma unroll
        for (int s = 0; s < CHS; ++s) {
            // ---- phase1 step s (independent work: fills phase2 stalls) ----
            if (buildNext) {
                const float w0 = l2 ? (s == 0 ? xc0 : cur[(s-1)*5+0]) : cur[s*5+0];
                const float w1 = l2 ? (s == 0 ? xc1 : cur[(s-1)*5+1]) : cur[s*5+1];
                const float w2 = l2 ? (s == 0 ? xc2 : cur[(s-1)*5+2]) : cur[s*5+2];
                const float w3 = l2 ? (s == 0 ? xc3 : cur[(s-1)*5+3]) : cur[s*5+3];
                const float xi = l2 ? 0.0f : cur[s*5+4];
#pragma unroll
                for (int g = 0; g < 4; ++g) {
                    float p = bbv[g];
                    p = fmaf(w0, wwh[0  + g], p);
                    p = fmaf(w1, wwh[4  + g], p);
                    p = fmaf(w2, wwh[8  + g], p);
                    p = fmaf(w3, wwh[12 + g], p);
                    pN[s][g] = fmaf(xi, wih[g], p);
                }
            }
            // ---- phase2 step s (serial recurrence, fused denominators) ----
            const float inv = h1x * l2f;           // odd: h1(t-1); even: 0
            float a0 = fmaf(h, whh[0], fmaf(inv, wih[0], pC[s][0]));
            float a1 = fmaf(h, whh[1], fmaf(inv, wih[1], pC[s][1]));
            float a2 = fmaf(h, whh[2], fmaf(inv, wih[2], pC[s][2]));
            float a3 = fmaf(h, whh[3], fmaf(inv, wih[3], pC[s][3]));
            a0 = fminf(a0, ACLAMP); a1 = fminf(a1, ACLAMP);
            a2 = fminf(a2, ACLAMP); a3 = fminf(a3, ACLAMP);
            const float eI = __builtin_amdgcn_exp2f(a0);   // e^{-a_i}
            const float eF = __builtin_amdgcn_exp2f(a1);   // e^{-a_f}
            const float eG = __builtin_amdgcn_exp2f(a2);   // e^{-2a_g}
            const float eO = __builtin_amdgcn_exp2f(a3);   // e^{-a_o}
            const float dI = 1.f + eI, dF = 1.f + eF;
            const float dG = 1.f + eG, dO = 1.f + eO;
            const float nG = 1.f - eG;
            // c' = c/dF + nG/(dI*dG)  ->  (c*dI*dG + nG*dF) / (dF*dI*dG)
            const float p   = dI * dG;
            const float num = fmaf(cc, p, nG * dF);
            const float den = dF * p;
            cc = num * __builtin_amdgcn_rcpf(den);
            // h = (1/dO) * (1-eC)/(1+eC),  eC = exp2(-2*log2e*c')
            const float Cm = fminf(cc * NEG2L, ACLAMP);
            const float eC = __builtin_amdgcn_exp2f(Cm);
            const float dC = 1.f + eC, nC = 1.f - eC;
            h = nC * __builtin_amdgcn_rcpf(dO * dC);

            if (s == 0) { if (is0 && l2) { h = 0.f; cc = 0.f; } }  // phantom reset

            ob[(s + CHS - 1) & (CHS - 1)] = fmaf(h, fw, fbv);

            if (s == 0 && l2 && c >= 1) {   // flush previous chunk's outputs
                orow[(c-1)*2+0] = make_float4(ob[0], ob[1], ob[2], ob[3]);
                orow[(c-1)*2+1] = make_float4(ob[4], ob[5], ob[6], ob[7]);
            }

            h1x = lane_swap(h);
        }
        if (buildNext) {
            xc0 = cur[35]; xc1 = cur[36]; xc2 = cur[37]; xc3 = cur[38];
        }
    };

    // ---- prologue: phase1(chunk 0) -> preA ----
    commit();
#pragma unroll
    for (int s = 0; s < CHS; ++s) {
        const float w0 = l2 ? (s == 0 ? 0.f : cur[(s-1)*5+0]) : cur[s*5+0];
        const float w1 = l2 ? (s == 0 ? 0.f : cur[(s-1)*5+1]) : cur[s*5+1];
        const float w2 = l2 ? (s == 0 ? 0.f : cur[(s-1)*5+2]) : cur[s*5+2];
        const float w3 = l2 ? (s == 0 ? 0.f : cur[(s-1)*5+3]) : cur[s*5+3];
        const float xi = l2 ? 0.0f : cur[s*5+4];
#pragma unroll
        for (int g = 0; g < 4; ++g) {
            float pp = bbv[g];
            pp = fmaf(w0, wwh[0  + g], pp);
            pp = fmaf(w1, wwh[4  + g], pp);
            pp = fmaf(w2, wwh[8  + g], pp);
            pp = fmaf(w3, wwh[12 + g], pp);
            preA[s][g] = fmaf(xi, wih[g], pp);
        }
    }
    xc0 = cur[35]; xc1 = cur[36]; xc2 = cur[37]; xc3 = cur[38];
    issue(1);

    // ---- main: 10 x 2 chunks, ping-pong pre buffers ----
    for (int cp = 0; cp < 10; ++cp) {
        const int c0 = 2 * cp;
        commit();                       // cur = chunk c0+1
        if (c0 + 2 < NCH) issue(c0 + 2);
        run_chunk(preA, preB, c0, true);

        commit();                       // cur = chunk c0+2
        if (c0 + 3 < NCH) issue(c0 + 3);
        run_chunk(preB, preA, c0 + 1, true);
    }

    // ---- last chunk (c=20): phase2 only ----
    run_chunk(preA, preB, NCH - 1, false);

    // ---- epilogue step t=168: odd lane computes h2(167) ----
    {
        float a[4];
#pragma unroll
        for (int g = 0; g < 4; ++g) {
            float pp = bbv[g];
            pp = fmaf(xc0, wwh[0  + g], pp);
            pp = fmaf(xc1, wwh[4  + g], pp);
            pp = fmaf(xc2, wwh[8  + g], pp);
            pp = fmaf(xc3, wwh[12 + g], pp);
            pp = fmaf(h1x, wih[g], pp);
            a[g] = fminf(fmaf(h, whh[g], pp), ACLAMP);
        }
        const float eI = __builtin_amdgcn_exp2f(a[0]);
        const float eF = __builtin_amdgcn_exp2f(a[1]);
        const float eG = __builtin_amdgcn_exp2f(a[2]);
        const float eO = __builtin_amdgcn_exp2f(a[3]);
        const float dI = 1.f + eI, dF = 1.f + eF;
        const float dG = 1.f + eG, dO = 1.f + eO;
        const float nG = 1.f - eG;
        const float p   = dI * dG;
        const float num = fmaf(cc, p, nG * dF);
        cc = num * __builtin_amdgcn_rcpf(dF * p);
        const float Cm = fminf(cc * NEG2L, ACLAMP);
        const float eC = __builtin_amdgcn_exp2f(Cm);
        h = (1.f - eC) * __builtin_amdgcn_rcpf(dO * (1.f + eC));
        ob[7] = fmaf(h, fw, fbv);
        if (l2) {
            orow[(NCH-1)*2+0] = make_float4(ob[0], ob[1], ob[2], ob[3]);
            orow[(NCH-1)*2+1] = make_float4(ob[4], ob[5], ob[6], ob[7]);
        }
    }
}

extern "C" void kernel_launch(void* const* d_in, const int* in_sizes, int n_in,
                              void* d_out, int out_size, void* d_ws, size_t ws_size,
                              hipStream_t stream) {
    const float* in   = (const float*)d_in[0];
    const float* W1ih = (const float*)d_in[1];
    const float* W1hh = (const float*)d_in[2];
    const float* W1wh = (const float*)d_in[3];
    const float* b1   = (const float*)d_in[4];
    const float* W2ih = (const float*)d_in[5];
    const float* W2hh = (const float*)d_in[6];
    const float* W2wh = (const float*)d_in[7];
    const float* b2   = (const float*)d_in[8];
    const float* fcw  = (const float*)d_in[9];
    const float* fcb  = (const float*)d_in[10];
    float* out = (float*)d_out;

    pewlstm_kernel<<<(BB * 2) / 64, 64, 0, stream>>>(
        in, W1ih, W1hh, W1wh, b1, W2ih, W2hh, W2wh, b2, fcw, fcb, out);
}